// Round 13
// baseline (72.413 us; speedup 1.0000x reference)
//
#include <hip/hip_runtime.h>
#include <hip/hip_bf16.h>
#include <math.h>

#define TOKS 16384
#define CDIM 1024
#define NEXP 8
#define RDIM 64
#define CAP  TOKS
#define NBLK_R 1024   // router blocks (16 tokens each)
#define UT_MAX 320    // max 64-token pair tiles: 16384/64 + 64

using f32x4   = __attribute__((ext_vector_type(4))) float;
using bf16x8  = __attribute__((ext_vector_type(8))) short;
using ushort8 = __attribute__((ext_vector_type(8))) unsigned short;

__device__ __forceinline__ ushort f2bf(float f) {
  unsigned u = __builtin_bit_cast(unsigned, f);
  u += 0x7fffu + ((u >> 16) & 1u);   // round-to-nearest-even
  return (ushort)(u >> 16);
}

// ---- setup: blocks 0..1023 = router (1024 thr, 16 waves, 1 token/wave);
//      blocks 1024..1279 = weight convert (1024 thr). (verified r11/r12)
__global__ __launch_bounds__(1024) void setup_kernel(
    const float* __restrict__ x, const float* __restrict__ rw_all,
    const float* __restrict__ rb_all, const int* __restrict__ key_id,
    const float* __restrict__ Wd, const float* __restrict__ Wu,
    float* __restrict__ imp_part,
    int* __restrict__ pbuf, float2* __restrict__ ggbuf,
    int* __restrict__ histT, ushort* __restrict__ xb,
    ushort* __restrict__ wdt, ushort* __restrict__ wut) {
  const int bid = blockIdx.x;
  const int tid = threadIdx.x;
  if (bid >= NBLK_R) {         // ---------------- weight convert ----------
    const int u = (bid - NBLK_R) * 1024 + tid;
    if (u < 131072) {          // Wd -> tile (e,s): [64 r][64 k], swizzled
      const int k4 = u & 255, r = (u >> 8) & 63, e = u >> 14;
      ushort4 h4;
      h4.x = f2bf(Wd[(size_t)(e * 1024 + k4 * 4 + 0) * 64 + r]);
      h4.y = f2bf(Wd[(size_t)(e * 1024 + k4 * 4 + 1) * 64 + r]);
      h4.z = f2bf(Wd[(size_t)(e * 1024 + k4 * 4 + 2) * 64 + r]);
      h4.w = f2bf(Wd[(size_t)(e * 1024 + k4 * 4 + 3) * 64 + r]);
      const int s = k4 >> 4;           // k-block (64-wide)
      const int kq4 = k4 & 15;         // ushort4 granule within row
      const int g = kq4 >> 1, hh = kq4 & 1;
      const int gs = g ^ (r & 7);      // pre-swizzle 8-ushort granule
      ((ushort4*)wdt)[((e * 16 + s) * 64 + r) * 16 + gs * 2 + hh] = h4;
    } else {                   // Wu -> tile (e,n0): [128 c][64 r], swizzled
      const int u2 = u - 131072;
      const int r4 = u2 & 15, c = (u2 >> 4) & 1023, e = u2 >> 14;
      ushort4 h4;
      h4.x = f2bf(Wu[(size_t)(e * 64 + r4 * 4 + 0) * 1024 + c]);
      h4.y = f2bf(Wu[(size_t)(e * 64 + r4 * 4 + 1) * 1024 + c]);
      h4.z = f2bf(Wu[(size_t)(e * 64 + r4 * 4 + 2) * 1024 + c]);
      h4.w = f2bf(Wu[(size_t)(e * 64 + r4 * 4 + 3) * 1024 + c]);
      const int n0 = c >> 7, cc = c & 127;
      const int g = r4 >> 1, hh = r4 & 1;
      const int gs = g ^ (cc & 7);
      ((ushort4*)wut)[((e * 8 + n0) * 128 + cc) * 16 + gs * 2 + hh] = h4;
    }
    return;
  }
  // ---------------- router (16 waves, 1 token each) ----------------
  __shared__ float4 s_rw[2112];        // 33 KB, permuted+padded (132/66)
  __shared__ float s_imp[16][NEXP];
  __shared__ int   s_pb[16];
  __shared__ float s_g1[16], s_g2[16];
  const int lane = tid & 63;
  const int wave = tid >> 6;           // 0..15 = token index in group
  const int kid = key_id[0];
  // stage rw[kid] -> LDS: coalesced read, padded scatter write.
  {
    const float4* rwg = (const float4*)rw_all + (size_t)kid * 2048;
#pragma unroll
    for (int j = 0; j < 2; ++j) {
      const int g = tid + j * 1024;
      const float4 v = rwg[g];
      const int C = g >> 1, h = g & 1;
      const int st = ((C >> 8) << 2) | (C & 3);
      const int l = (C >> 2) & 63;
      s_rw[st * 132 + h * 66 + l] = v;
    }
  }
  __syncthreads();

  const float* rb = rb_all + (size_t)kid * NEXP;
  const int eln = ((lane & 1) << 2) | (lane & 2) | ((lane >> 2) & 1);
  const float rbe = rb[eln];

  const int token = bid * 16 + wave;
  const float* xr = x + (size_t)token * CDIM + lane * 4;
  float4 xv[4];
#pragma unroll
  for (int j = 0; j < 4; ++j) xv[j] = *(const float4*)(xr + j * 256);
  ushort* xo = xb + (size_t)token * CDIM + lane * 4;
#pragma unroll
  for (int j = 0; j < 4; ++j) {
    ushort4 h;
    h.x = f2bf(xv[j].x); h.y = f2bf(xv[j].y);
    h.z = f2bf(xv[j].z); h.w = f2bf(xv[j].w);
    *(ushort4*)(xo + j * 256) = h;
  }
  float acc[8];
#pragma unroll
  for (int e = 0; e < 8; ++e) acc[e] = 0.f;
#pragma unroll
  for (int j = 0; j < 4; ++j) {
#pragma unroll
    for (int i = 0; i < 4; ++i) {
      const int st = j * 4 + i;
      const float4 wA = s_rw[st * 132 + lane];
      const float4 wB = s_rw[st * 132 + 66 + lane];
      const float xi = (&xv[j].x)[i];
      acc[0] = fmaf(xi, wA.x, acc[0]);
      acc[1] = fmaf(xi, wA.y, acc[1]);
      acc[2] = fmaf(xi, wA.z, acc[2]);
      acc[3] = fmaf(xi, wA.w, acc[3]);
      acc[4] = fmaf(xi, wB.x, acc[4]);
      acc[5] = fmaf(xi, wB.y, acc[5]);
      acc[6] = fmaf(xi, wB.z, acc[6]);
      acc[7] = fmaf(xi, wB.w, acc[7]);
    }
  }
  // butterfly 8 accs -> 1 (expert = bitrev3(lane&7)), then 64-lane sum
#pragma unroll
  for (int i = 0; i < 4; ++i) {
    const float send = (lane & 1) ? acc[i] : acc[i + 4];
    const float recv = __shfl_xor(send, 1);
    acc[i] = ((lane & 1) ? acc[i + 4] : acc[i]) + recv;
  }
#pragma unroll
  for (int i = 0; i < 2; ++i) {
    const float send = (lane & 2) ? acc[i] : acc[i + 2];
    const float recv = __shfl_xor(send, 2);
    acc[i] = ((lane & 2) ? acc[i + 2] : acc[i]) + recv;
  }
  {
    const float send = (lane & 4) ? acc[0] : acc[1];
    const float recv = __shfl_xor(send, 4);
    acc[0] = ((lane & 4) ? acc[1] : acc[0]) + recv;
  }
  float v = acc[0];
  v += __shfl_xor(v, 8); v += __shfl_xor(v, 16); v += __shfl_xor(v, 32);

  const float logit = v + rbe;
  float mx = logit;
  mx = fmaxf(mx, __shfl_xor(mx, 1));
  mx = fmaxf(mx, __shfl_xor(mx, 2));
  mx = fmaxf(mx, __shfl_xor(mx, 4));
  const float ex = expf(logit - mx);
  float sm = ex;
  sm += __shfl_xor(sm, 1); sm += __shfl_xor(sm, 2); sm += __shfl_xor(sm, 4);
  const float p = ex / sm;
  float bv = p; int bi = eln;
#pragma unroll
  for (int mk = 1; mk <= 4; mk <<= 1) {
    const float ov = __shfl_xor(bv, mk);
    const int oi = __shfl_xor(bi, mk);
    if (ov > bv || (ov == bv && oi < bi)) { bv = ov; bi = oi; }
  }
  const int e1 = bi; const float v1 = bv;
  float cv = (eln == e1) ? -1.f : p; int ci = eln;
#pragma unroll
  for (int mk = 1; mk <= 4; mk <<= 1) {
    const float ov = __shfl_xor(cv, mk);
    const int oi = __shfl_xor(ci, mk);
    if (ov > cv || (ov == cv && oi < ci)) { cv = ov; ci = oi; }
  }
  const int e2 = ci; const float v2 = cv;

  if (lane == 0) {
    const float gs = 1.f / (v1 + v2);
    s_g1[wave] = v1 * gs;
    s_g2[wave] = v2 * gs;
    s_pb[wave] = e1 * 8 + e2;
  }
  if (lane < 8) s_imp[wave][eln] = p;   // per-expert prob of this token
  __syncthreads();
  if (tid < 8) {
    float s = 0.f;
#pragma unroll
    for (int wv = 0; wv < 16; ++wv) s += s_imp[wv][tid];
    imp_part[bid * 8 + tid] = s;
  }
  // per-token records (coalesced, block-contiguous)
  if (tid < 16) {
    pbuf[bid * 16 + tid] = s_pb[tid];
    ggbuf[bid * 16 + tid] = make_float2(s_g1[tid], s_g2[tid]);
  }
  // transposed histograms: histT[c*1024 + blk], c in [0,80)
  if (tid < 80) {
    int c = 0;
    if (tid < 16) {
      const int k = tid >> 3, e = tid & 7;
#pragma unroll
      for (int j = 0; j < 16; ++j)
        c += ((k ? (s_pb[j] & 7) : (s_pb[j] >> 3)) == e) ? 1 : 0;
    } else {
      const int b = tid - 16;
#pragma unroll
      for (int j = 0; j < 16; ++j) c += (s_pb[j] == b) ? 1 : 0;
    }
    histT[tid * 1024 + bid] = c;
  }
}

// -------- scan: one block per counter, parallel prefix over 1024 blocks ----
__global__ __launch_bounds__(256) void scan_kernel(
    const int* __restrict__ histT, int* __restrict__ baseT,
    int* __restrict__ cnt, int* __restrict__ cnt_pair) {
  __shared__ int ls[256];
  const int c = blockIdx.x;
  const int t = threadIdx.x;
  const int4 v = ((const int4*)(histT + (c << 10)))[t];
  const int s = v.x + v.y + v.z + v.w;
  ls[t] = s;
  __syncthreads();
#pragma unroll
  for (int off = 1; off < 256; off <<= 1) {
    const int add = (t >= off) ? ls[t - off] : 0;
    __syncthreads();
    ls[t] += add;
    __syncthreads();
  }
  const int incl = ls[t];
  const int excl = incl - s;
  int4 b;
  b.x = excl;
  b.y = excl + v.x;
  b.z = excl + v.x + v.y;
  b.w = excl + v.x + v.y + v.z;
  ((int4*)(baseT + (c << 10)))[t] = b;
  if (t == 255) {
    if (c < 16) cnt[c * 32] = incl;
    else        cnt_pair[(c - 16) * 32] = incl;
  }
}

// -------- scatter (blocks 0..255: pairlist only) + plan (block 256) --------
// Single plan: 64-token pair tiles shared by down AND up (identical tiling).
__global__ __launch_bounds__(256) void scatter_kernel(
    const int* __restrict__ baseT, const int* __restrict__ pbuf,
    const int* __restrict__ cnt_pair,
    int* __restrict__ pairlist,
    int* __restrict__ uplan, int* __restrict__ totals) {
  if (blockIdx.x == 256) {
    __shared__ int uoff[64];
    const int t = threadIdx.x;
    if (t == 0) {
      int a = 0;
      for (int b2 = 0; b2 < 64; ++b2) { uoff[b2] = a; a += (cnt_pair[b2 * 32] + 63) >> 6; }
      totals[1] = a;
    }
    __syncthreads();
    if (t < 64) {
      const int nu = (cnt_pair[t * 32] + 63) >> 6;
      for (int i = 0; i < nu; ++i) uplan[uoff[t] + i] = (t << 16) | i;
    }
    return;
  }
  const int tid = threadIdx.x;
  const int lane = tid & 63;
  const int wave = tid >> 6;
  const int rb = blockIdx.x * 4 + wave;   // router block, 0..1023
  const int i = lane;
  int pb = 0;
  if (lane < 16) pb = pbuf[rb * 16 + lane];
  int rp = 0;
#pragma unroll
  for (int j = 0; j < 15; ++j) {
    const int q = __shfl(pb, j);
    if (j < i) rp += (q == pb) ? 1 : 0;
  }
  if (lane < 16) {
    const int token = rb * 16 + i;
    const int sp = baseT[((16 + pb) << 10) + rb] + rp;
    pairlist[pb * CAP + sp] = token;
  }
}

// ---- down (64-token pair tiles): compute BOTH experts' H per tile.
// H0 = GELU(x@Wd_e1)*g1 -> Hbuf[tok]; H1 = GELU(x@Wd_e2)*g2 -> Hbuf[TOKS+tok].
// xb staged ONCE per token; weight traffic 256KB per 64 tokens (vs per 32 in
// r12). Hs0/Hs1 ALIAS BsA/BsB after the K-loop (barrier-protected) -> LDS
// 25KB -> 6 blocks/CU. Waves: (w<2 -> e1 | e2), row-half = w&1; 8 MFMA/step.
__global__ __launch_bounds__(256) void down_kernel(
    const ushort* __restrict__ xb, const ushort* __restrict__ wdt,
    const int* __restrict__ cnt_pair, const int* __restrict__ pairlist,
    const float2* __restrict__ ggbuf,
    const int* __restrict__ uplan, const int* __restrict__ totals,
    ushort* __restrict__ Hbuf) {
  if (blockIdx.x >= totals[1]) return;
  const int ent = uplan[blockIdx.x];
  const int b = ent >> 16, tile = ent & 0xffff;
  const int ea = b >> 3, eb = b & 7;
  const int n = cnt_pair[b * 32];
  const int start = tile * 64;

  __shared__ __align__(16) char smem[25344];
  ushort* As  = (ushort*)(smem);            // 8 KB (64x64)
  ushort* BsA = (ushort*)(smem + 8192);     // 8 KB (64x64, e1)
  ushort* BsB = (ushort*)(smem + 16384);    // 8 KB (64x64, e2)
  ushort* Hs0 = (ushort*)(smem + 8192);     // aliases BsA after K-loop
  ushort* Hs1 = (ushort*)(smem + 16384);    // aliases BsB after K-loop
  int*  toks  = (int*)(smem + 24576);       // 256 B
  float* g1s  = (float*)(smem + 24832);     // 256 B
  float* g2s  = (float*)(smem + 25088);     // 256 B

  const int tid = threadIdx.x;
  const int lane = tid & 63;
  const int w = tid >> 6;

  if (tid < 64) {
    int tk = -1; float2 gg = make_float2(0.f, 0.f);
    if (start + tid < n) {
      tk = pairlist[b * CAP + start + tid];
      gg = ggbuf[tk];
    }
    toks[tid] = tk; g1s[tid] = gg.x; g2s[tid] = gg.y;
  }
  __syncthreads();

  // staging: thread t covers chunk t (row t>>3) and chunk t+256 (row+32).
  // A: source col swizzled per row (xb natural layout); LDS write LINEAR.
  // B: wdt tiles pre-swizzled in global; LINEAR copy.
  const int row0 = tid >> 3;
  const int g8 = (tid & 7) * 8;
  const int csw = g8 ^ ((row0 & 7) << 3);   // (row0+32)&7 == row0&7
  const int tk0 = toks[row0], tk1 = toks[row0 + 32];
  const ushort* xr0 = xb + (size_t)(tk0 < 0 ? 0 : tk0) * CDIM + csw;
  const ushort* xr1 = xb + (size_t)(tk1 < 0 ? 0 : tk1) * CDIM + csw;
  const ushort* wdA = wdt + ((size_t)ea << 16);   // 16 tiles x 4096 ushorts
  const ushort* wdB = wdt + ((size_t)eb << 16);

  f32x4 acc[2][4];
#pragma unroll
  for (int m = 0; m < 2; ++m)
#pragma unroll
    for (int nn = 0; nn < 4; ++nn) acc[m][nn] = (f32x4){0.f, 0.f, 0.f, 0.f};

  ushort8 rA0, rA1, rBA0, rBA1, rBB0, rBB1;
  rA0  = *(const ushort8*)(xr0);
  rA1  = *(const ushort8*)(xr1);
  rBA0 = *(const ushort8*)(wdA + tid * 8);
  rBA1 = *(const ushort8*)(wdA + tid * 8 + 2048);
  rBB0 = *(const ushort8*)(wdB + tid * 8);
  rBB1 = *(const ushort8*)(wdB + tid * 8 + 2048);

#pragma unroll 1
  for (int s = 0; s < 16; ++s) {
    __syncthreads();                       // prev step's LDS reads done
    *(ushort8*)&As [tid * 8]        = rA0;
    *(ushort8*)&As [tid * 8 + 2048] = rA1;
    *(ushort8*)&BsA[tid * 8]        = rBA0;
    *(ushort8*)&BsA[tid * 8 + 2048] = rBA1;
    *(ushort8*)&BsB[tid * 8]        = rBB0;
    *(ushort8*)&BsB[tid * 8 + 2048] = rBB1;
    if (s < 15) {                          // prefetch step s+1 under MFMA
      rA0  = *(const ushort8*)(xr0 + (s + 1) * 64);
      rA1  = *(const ushort8*)(xr1 + (s + 1) * 64);
      rBA0 = *(const ushort8*)(wdA + ((s + 1) << 12) + tid * 8);
      rBA1 = *(const ushort8*)(wdA + ((s + 1) << 12) + tid * 8 + 2048);
      rBB0 = *(const ushort8*)(wdB + ((s + 1) << 12) + tid * 8);
      rBB1 = *(const ushort8*)(wdB + ((s + 1) << 12) + tid * 8 + 2048);
    }
    __syncthreads();
    const ushort* Bsx = (w < 2) ? BsA : BsB;
    const int rh = (w & 1) * 32;           // row half
#pragma unroll
    for (int kk = 0; kk < 64; kk += 32) {
      const int kb = kk + (lane >> 4) * 8;
      bf16x8 a[2], bb[4];
#pragma unroll
      for (int m = 0; m < 2; ++m) {
        const int row = rh + m * 16 + (lane & 15);
        a[m] = *(const bf16x8*)&As[row * 64 + (kb ^ ((row & 7) << 3))];
      }
#pragma unroll
      for (int nn = 0; nn < 4; ++nn) {
        const int r = nn * 16 + (lane & 15);
        bb[nn] = *(const bf16x8*)&Bsx[r * 64 + (kb ^ ((r & 7) << 3))];
      }
#pragma unroll
      for (int m = 0; m < 2; ++m)
#pragma unroll
        for (int nn = 0; nn < 4; ++nn)
          acc[m][nn] = __builtin_amdgcn_mfma_f32_16x16x32_bf16(a[m], bb[nn], acc[m][nn], 0, 0, 0);
    }
  }
  __syncthreads();                         // all MFMA LDS reads done (alias!)

  // epilogue: GELU*gate -> Hs0 (waves 0,1) / Hs1 (waves 2,3); rows rh..rh+31
  {
    ushort* Hsx = (w < 2) ? Hs0 : Hs1;
    const float* gsx = (w < 2) ? g1s : g2s;
    const int rh = (w & 1) * 32;
#pragma unroll
    for (int m = 0; m < 2; ++m)
#pragma unroll
      for (int nn = 0; nn < 4; ++nn)
#pragma unroll
        for (int q = 0; q < 4; ++q) {
          const int slot = rh + m * 16 + (lane >> 4) * 4 + q;
          const int r = nn * 16 + (lane & 15);
          const float v = acc[m][nn][q];
          const float ge = 0.5f * v * (1.f + erff(v * 0.70710678118654752f));
          Hsx[slot * 64 + (r ^ ((slot & 7) << 3))] = f2bf(ge * gsx[slot]);
        }
  }
  __syncthreads();
  // writeout: thread covers rows row0 and row0+32 of both halves
  const int lof0 = row0 * 64 + (g8 ^ ((row0 & 7) << 3));
  const int lof1 = (row0 + 32) * 64 + (g8 ^ ((row0 & 7) << 3));
  if (tk0 >= 0) {
    *(ushort8*)(Hbuf + (size_t)tk0 * 64 + g8) = *(const ushort8*)&Hs0[lof0];
    *(ushort8*)(Hbuf + ((size_t)TOKS + tk0) * 64 + g8) = *(const ushort8*)&Hs1[lof0];
  }
  if (tk1 >= 0) {
    *(ushort8*)(Hbuf + (size_t)tk1 * 64 + g8) = *(const ushort8*)&Hs0[lof1];
    *(ushort8*)(Hbuf + ((size_t)TOKS + tk1) * 64 + g8) = *(const ushort8*)&Hs1[lof1];
  }
}

// ---- up: out[t] = H0[t]@Wu_ea + H1[t]@Wu_eb, 64-tok x 2 col-slices --------
// (verified r9-r12) A0/A1 staged ONCE per block; slice-1 weights
// reg-prefetched under slice-0 MFMAs. Block x==UT_MAX runs aux.
__global__ __launch_bounds__(256) void up_kernel(
    const ushort* __restrict__ Hbuf, const ushort* __restrict__ wut,
    const int* __restrict__ cnt_pair, const int* __restrict__ pairlist,
    const int* __restrict__ uplan, const int* __restrict__ totals,
    const int* __restrict__ cnt, const float* __restrict__ imp_part,
    float* __restrict__ out) {
  __shared__ __align__(16) char smem[49664];
  if (blockIdx.x == UT_MAX) {          // aux block (y==0 only)
    if (blockIdx.y != 0) return;
    float* red = (float*)smem;
    float* tot = (float*)(smem + 1024);
    const int t = threadIdx.x;
    const int e = t & 7, b0 = t >> 3;
    float s = 0.f;
    for (int j = 0; j < NBLK_R / 32; ++j)
      s += imp_part[(b0 + 32 * j) * 8 + e];
    red[t] = s;
    __syncthreads();
    if (t < 8) {
      float tt = 0.f;
      for (int ww = 0; ww < 32; ++ww) tt += red[ww * 8 + t];
      tot[t] = tt;
    }
    __syncthreads();
    if (t == 0) {
      float a = 0.f;
#pragma unroll
      for (int ee = 0; ee < NEXP; ++ee)
        a += (tot[ee] / (float)TOKS) *
             ((float)(cnt[ee * 32] + cnt[(NEXP + ee) * 32]) / (float)(2 * TOKS));
      out[(size_t)TOKS * CDIM] = 0.001f * 8.f * a;
    }
    return;
  }
  if (blockIdx.x >= totals[1]) return;
  const int ent = uplan[blockIdx.x];
  const int b = ent >> 16, tile = ent & 0xffff;
  const int ea = b >> 3, eb = b & 7;
  const int n = cnt_pair[b * 32];
  const int start = tile * 64;
  const int ybase = blockIdx.y * 2;    // 2 slices per block

  ushort* A0  = (ushort*)(smem);            // 8 KB (64x64)
  ushort* A1  = (ushort*)(smem + 8192);     // 8 KB
  ushort* BuA = (ushort*)(smem + 16384);    // 16 KB (128x64)
  ushort* BuB = (ushort*)(smem + 32768);    // 16 KB
  int*  toks  = (int*)(smem + 49152);       // 256 B

  const int tid = threadIdx.x;
  const int lane = tid & 63;
  const int w = tid >> 6;
  const int wr = w >> 1, wc = w & 1;

  if (tid < 64) {
    int tk = -1;
    if (start + tid < n) tk = pairlist[b * CAP + start + tid];
    toks[tid] = tk;
  }
  __syncthreads();

  // issue slice-0 weight loads (pre-swizzled wut; linear copy)
  const ushort* wuA = wut + ((size_t)(ea * 8 + ybase)) * 8192;
  const ushort* wuB = wut + ((size_t)(eb * 8 + ybase)) * 8192;
  ushort8 rUA[4], rUB[4];
#pragma unroll
  for (int j = 0; j < 4; ++j) {
    rUA[j] = *(const ushort8*)(wuA + (tid + j * 256) * 8);
    rUB[j] = *(const ushort8*)(wuB + (tid + j * 256) * 8);
  }
  // A-gather (source col swizzled; LDS linear) — ONCE per block
  const int row0 = tid >> 3;
  const int g8 = (tid & 7) * 8;
  const int csw = g8 ^ ((row0 & 7) << 3);
  const int tk0 = toks[row0], tk1 = toks[row0 + 32];
  const size_t t0 = (size_t)(tk0 < 0 ? 0 : tk0);
  const size_t t1 = (size_t)(tk1 < 0 ? 0 : tk1);
  *(ushort8*)&A0[tid * 8]        = *(const ushort8*)(Hbuf + t0 * 64 + csw);
  *(ushort8*)&A0[tid * 8 + 2048] = *(const ushort8*)(Hbuf + t1 * 64 + csw);
  *(ushort8*)&A1[tid * 8]        = *(const ushort8*)(Hbuf + (TOKS + t0) * 64 + csw);
  *(ushort8*)&A1[tid * 8 + 2048] = *(const ushort8*)(Hbuf + (TOKS + t1) * 64 + csw);
  // write slice-0 weights
#pragma unroll
  for (int j = 0; j < 4; ++j) {
    *(ushort8*)&BuA[(tid + j * 256) * 8] = rUA[j];
    *(ushort8*)&BuB[(tid + j * 256) * 8] = rUB[j];
  }
  __syncthreads();

#pragma unroll 1
  for (int j2 = 0; j2 < 2; ++j2) {
    const int n0 = ybase + j2;
    if (j2 == 0) {                      // prefetch slice-1 weights under MFMA
#pragma unroll
      for (int j = 0; j < 4; ++j) {
        rUA[j] = *(const ushort8*)(wuA + 8192 + (tid + j * 256) * 8);
        rUB[j] = *(const ushort8*)(wuB + 8192 + (tid + j * 256) * 8);
      }
    }
    f32x4 uac[2][4];
#pragma unroll
    for (int m = 0; m < 2; ++m)
#pragma unroll
      for (int nn = 0; nn < 4; ++nn) uac[m][nn] = (f32x4){0.f, 0.f, 0.f, 0.f};
    // pass A: H0 @ Wu_ea
#pragma unroll
    for (int kk = 0; kk < 64; kk += 32) {
      const int kb = kk + (lane >> 4) * 8;
      bf16x8 a[2], bbv[4];
#pragma unroll
      for (int m = 0; m < 2; ++m) {
        const int row = wr * 32 + m * 16 + (lane & 15);
        a[m] = *(const bf16x8*)&A0[row * 64 + (kb ^ ((row & 7) << 3))];
      }
#pragma unroll
      for (int nn = 0; nn < 4; ++nn) {
        const int c = wc * 64 + nn * 16 + (lane & 15);
        bbv[nn] = *(const bf16x8*)&BuA[c * 64 + (kb ^ ((c & 7) << 3))];
      }
#pragma unroll
      for (int m = 0; m < 2; ++m)
#pragma unroll
        for (int nn = 0; nn < 4; ++nn)
          uac[m][nn] = __builtin_amdgcn_mfma_f32_16x16x32_bf16(a[m], bbv[nn], uac[m][nn], 0, 0, 0);
    }
    // pass B: H1 @ Wu_eb (accumulate)
#pragma unroll
    for (int kk = 0; kk < 64; kk += 32) {
      const int kb = kk + (lane >> 4) * 8;
      bf16x8 a[2], bbv[4];
#pragma unroll
      for (int m = 0; m < 2; ++m) {
        const int row = wr * 32 + m * 16 + (lane & 15);
        a[m] = *(const bf16x8*)&A1[row * 64 + (kb ^ ((row & 7) << 3))];
      }
#pragma unroll
      for (int nn = 0; nn < 4; ++nn) {
        const int c = wc * 64 + nn * 16 + (lane & 15);
        bbv[nn] = *(const bf16x8*)&BuB[c * 64 + (kb ^ ((c & 7) << 3))];
      }
#pragma unroll
      for (int m = 0; m < 2; ++m)
#pragma unroll
        for (int nn = 0; nn < 4; ++nn)
          uac[m][nn] = __builtin_amdgcn_mfma_f32_16x16x32_bf16(a[m], bbv[nn], uac[m][nn], 0, 0, 0);
    }
    if (j2 == 0) {
      __syncthreads();                  // all waves done reading Bu
#pragma unroll
      for (int j = 0; j < 4; ++j) {
        *(ushort8*)&BuA[(tid + j * 256) * 8] = rUA[j];
        *(ushort8*)&BuB[(tid + j * 256) * 8] = rUB[j];
      }
    }
    // store this 128-col slice
#pragma unroll
    for (int m = 0; m < 2; ++m)
#pragma unroll
      for (int q = 0; q < 4; ++q) {
        const int slot = wr * 32 + m * 16 + (lane >> 4) * 4 + q;
        const int tk = toks[slot];
        if (tk >= 0) {
          float* orow = out + (size_t)tk * CDIM + n0 * 128 + wc * 64 + (lane & 15);
#pragma unroll
          for (int nn = 0; nn < 4; ++nn) orow[nn * 16] = uac[m][nn][q];
        }
      }
    if (j2 == 0) __syncthreads();       // Bu writes visible for slice 1
  }
}

extern "C" void kernel_launch(void* const* d_in, const int* in_sizes, int n_in,
                              void* d_out, int out_size, void* d_ws, size_t ws_size,
                              hipStream_t stream) {
  const float* x   = (const float*)d_in[0];
  const float* rw  = (const float*)d_in[1];
  const float* rb  = (const float*)d_in[2];
  const float* Wd  = (const float*)d_in[3];
  const float* Wu  = (const float*)d_in[4];
  const int* key_id = (const int*)d_in[5];
  float* out = (float*)d_out;

  char* ws = (char*)d_ws;
  int*    cnt      = (int*)ws;                    // 2 KB  (16 x 128B)
  int*    cnt_pair = (int*)(ws + 2048);           // 8 KB  (64 x 128B)
  int*    totals   = (int*)(ws + 10240);          // 8 B
  float*  imp_part = (float*)(ws + 16384);        // 32 KB
  int*    uplan    = (int*)(ws + 57344);          // ~1.3 KB
  int*    pbuf     = (int*)(ws + 65536);          // 64 KB
  float2* ggbuf    = (float2*)(ws + 131072);      // 128 KB (read by down)
  ushort* wdt      = (ushort*)(ws + 2162688);     // 1 MB
  ushort* wut      = (ushort*)(ws + 3211264);     // 1 MB
  ushort* xb       = (ushort*)(ws + 4259840);     // 32 MB -> 37814272
  int*    pairlist = (int*)(ws + 37847040);       // 4 MB  -> 42041344
  ushort* Hbuf     = (ushort*)(ws + 42041344);    // 4 MB  -> 46235648

  // histT/baseT ALIAS the Hbuf region: fully consumed by scan/scatter before
  // down_kernel writes Hbuf.
  int*    histT = (int*)(ws + 42041344);                // 320 KB
  int*    baseT = (int*)(ws + 42041344 + 327680);       // 320 KB

  setup_kernel<<<NBLK_R + 256, 1024, 0, stream>>>(
      x, rw, rb, key_id, Wd, Wu, imp_part, pbuf, ggbuf, histT, xb, wdt, wut);
  scan_kernel<<<80, 256, 0, stream>>>(histT, baseT, cnt, cnt_pair);
  scatter_kernel<<<257, 256, 0, stream>>>(baseT, pbuf, cnt_pair,
                                          pairlist, uplan, totals);
  down_kernel<<<UT_MAX, 256, 0, stream>>>(xb, wdt, cnt_pair, pairlist, ggbuf,
                                          uplan, totals, Hbuf);
  up_kernel<<<dim3(UT_MAX + 1, 4), 256, 0, stream>>>(
      Hbuf, wut, cnt_pair, pairlist, uplan, totals, cnt, imp_part, out);
}

// Round 14
// 70.927 us; speedup vs baseline: 1.0210x; 1.0210x over previous
//
#include <hip/hip_runtime.h>
#include <hip/hip_bf16.h>
#include <math.h>

#define TOKS 16384
#define CDIM 1024
#define NEXP 8
#define RDIM 64
#define CAP  TOKS
#define NBLK_R 1024   // router blocks (16 tokens each)
#define UT_MAX 320    // max 64-token pair tiles: 16384/64 + 64

using f32x4   = __attribute__((ext_vector_type(4))) float;
using bf16x8  = __attribute__((ext_vector_type(8))) short;
using ushort8 = __attribute__((ext_vector_type(8))) unsigned short;

__device__ __forceinline__ ushort f2bf(float f) {
  unsigned u = __builtin_bit_cast(unsigned, f);
  u += 0x7fffu + ((u >> 16) & 1u);   // round-to-nearest-even
  return (ushort)(u >> 16);
}

// ---- setup: blocks 0..1023 = router (1024 thr, 16 waves, 1 token/wave);
//      blocks 1024..1279 = weight convert (1024 thr). (verified r11-r13)
__global__ __launch_bounds__(1024) void setup_kernel(
    const float* __restrict__ x, const float* __restrict__ rw_all,
    const float* __restrict__ rb_all, const int* __restrict__ key_id,
    const float* __restrict__ Wd, const float* __restrict__ Wu,
    float* __restrict__ imp_part,
    int* __restrict__ pbuf, float2* __restrict__ ggbuf,
    int* __restrict__ histT, ushort* __restrict__ xb,
    ushort* __restrict__ wdt, ushort* __restrict__ wut) {
  const int bid = blockIdx.x;
  const int tid = threadIdx.x;
  if (bid >= NBLK_R) {         // ---------------- weight convert ----------
    const int u = (bid - NBLK_R) * 1024 + tid;
    if (u < 131072) {          // Wd -> tile (e,s): [64 r][64 k], swizzled
      const int k4 = u & 255, r = (u >> 8) & 63, e = u >> 14;
      ushort4 h4;
      h4.x = f2bf(Wd[(size_t)(e * 1024 + k4 * 4 + 0) * 64 + r]);
      h4.y = f2bf(Wd[(size_t)(e * 1024 + k4 * 4 + 1) * 64 + r]);
      h4.z = f2bf(Wd[(size_t)(e * 1024 + k4 * 4 + 2) * 64 + r]);
      h4.w = f2bf(Wd[(size_t)(e * 1024 + k4 * 4 + 3) * 64 + r]);
      const int s = k4 >> 4;           // k-block (64-wide)
      const int kq4 = k4 & 15;         // ushort4 granule within row
      const int g = kq4 >> 1, hh = kq4 & 1;
      const int gs = g ^ (r & 7);      // pre-swizzle 8-ushort granule
      ((ushort4*)wdt)[((e * 16 + s) * 64 + r) * 16 + gs * 2 + hh] = h4;
    } else {                   // Wu -> tile (e,n0): [128 c][64 r], swizzled
      const int u2 = u - 131072;
      const int r4 = u2 & 15, c = (u2 >> 4) & 1023, e = u2 >> 14;
      ushort4 h4;
      h4.x = f2bf(Wu[(size_t)(e * 64 + r4 * 4 + 0) * 1024 + c]);
      h4.y = f2bf(Wu[(size_t)(e * 64 + r4 * 4 + 1) * 1024 + c]);
      h4.z = f2bf(Wu[(size_t)(e * 64 + r4 * 4 + 2) * 1024 + c]);
      h4.w = f2bf(Wu[(size_t)(e * 64 + r4 * 4 + 3) * 1024 + c]);
      const int n0 = c >> 7, cc = c & 127;
      const int g = r4 >> 1, hh = r4 & 1;
      const int gs = g ^ (cc & 7);
      ((ushort4*)wut)[((e * 8 + n0) * 128 + cc) * 16 + gs * 2 + hh] = h4;
    }
    return;
  }
  // ---------------- router (16 waves, 1 token each) ----------------
  __shared__ float4 s_rw[2112];        // 33 KB, permuted+padded (132/66)
  __shared__ float s_imp[16][NEXP];
  __shared__ int   s_pb[16];
  __shared__ float s_g1[16], s_g2[16];
  const int lane = tid & 63;
  const int wave = tid >> 6;           // 0..15 = token index in group
  const int kid = key_id[0];
  // stage rw[kid] -> LDS: coalesced read, padded scatter write.
  {
    const float4* rwg = (const float4*)rw_all + (size_t)kid * 2048;
#pragma unroll
    for (int j = 0; j < 2; ++j) {
      const int g = tid + j * 1024;
      const float4 v = rwg[g];
      const int C = g >> 1, h = g & 1;
      const int st = ((C >> 8) << 2) | (C & 3);
      const int l = (C >> 2) & 63;
      s_rw[st * 132 + h * 66 + l] = v;
    }
  }
  __syncthreads();

  const float* rb = rb_all + (size_t)kid * NEXP;
  const int eln = ((lane & 1) << 2) | (lane & 2) | ((lane >> 2) & 1);
  const float rbe = rb[eln];

  const int token = bid * 16 + wave;
  const float* xr = x + (size_t)token * CDIM + lane * 4;
  float4 xv[4];
#pragma unroll
  for (int j = 0; j < 4; ++j) xv[j] = *(const float4*)(xr + j * 256);
  ushort* xo = xb + (size_t)token * CDIM + lane * 4;
#pragma unroll
  for (int j = 0; j < 4; ++j) {
    ushort4 h;
    h.x = f2bf(xv[j].x); h.y = f2bf(xv[j].y);
    h.z = f2bf(xv[j].z); h.w = f2bf(xv[j].w);
    *(ushort4*)(xo + j * 256) = h;
  }
  float acc[8];
#pragma unroll
  for (int e = 0; e < 8; ++e) acc[e] = 0.f;
#pragma unroll
  for (int j = 0; j < 4; ++j) {
#pragma unroll
    for (int i = 0; i < 4; ++i) {
      const int st = j * 4 + i;
      const float4 wA = s_rw[st * 132 + lane];
      const float4 wB = s_rw[st * 132 + 66 + lane];
      const float xi = (&xv[j].x)[i];
      acc[0] = fmaf(xi, wA.x, acc[0]);
      acc[1] = fmaf(xi, wA.y, acc[1]);
      acc[2] = fmaf(xi, wA.z, acc[2]);
      acc[3] = fmaf(xi, wA.w, acc[3]);
      acc[4] = fmaf(xi, wB.x, acc[4]);
      acc[5] = fmaf(xi, wB.y, acc[5]);
      acc[6] = fmaf(xi, wB.z, acc[6]);
      acc[7] = fmaf(xi, wB.w, acc[7]);
    }
  }
  // butterfly 8 accs -> 1 (expert = bitrev3(lane&7)), then 64-lane sum
#pragma unroll
  for (int i = 0; i < 4; ++i) {
    const float send = (lane & 1) ? acc[i] : acc[i + 4];
    const float recv = __shfl_xor(send, 1);
    acc[i] = ((lane & 1) ? acc[i + 4] : acc[i]) + recv;
  }
#pragma unroll
  for (int i = 0; i < 2; ++i) {
    const float send = (lane & 2) ? acc[i] : acc[i + 2];
    const float recv = __shfl_xor(send, 2);
    acc[i] = ((lane & 2) ? acc[i + 2] : acc[i]) + recv;
  }
  {
    const float send = (lane & 4) ? acc[0] : acc[1];
    const float recv = __shfl_xor(send, 4);
    acc[0] = ((lane & 4) ? acc[1] : acc[0]) + recv;
  }
  float v = acc[0];
  v += __shfl_xor(v, 8); v += __shfl_xor(v, 16); v += __shfl_xor(v, 32);

  const float logit = v + rbe;
  float mx = logit;
  mx = fmaxf(mx, __shfl_xor(mx, 1));
  mx = fmaxf(mx, __shfl_xor(mx, 2));
  mx = fmaxf(mx, __shfl_xor(mx, 4));
  const float ex = expf(logit - mx);
  float sm = ex;
  sm += __shfl_xor(sm, 1); sm += __shfl_xor(sm, 2); sm += __shfl_xor(sm, 4);
  const float p = ex / sm;
  float bv = p; int bi = eln;
#pragma unroll
  for (int mk = 1; mk <= 4; mk <<= 1) {
    const float ov = __shfl_xor(bv, mk);
    const int oi = __shfl_xor(bi, mk);
    if (ov > bv || (ov == bv && oi < bi)) { bv = ov; bi = oi; }
  }
  const int e1 = bi; const float v1 = bv;
  float cv = (eln == e1) ? -1.f : p; int ci = eln;
#pragma unroll
  for (int mk = 1; mk <= 4; mk <<= 1) {
    const float ov = __shfl_xor(cv, mk);
    const int oi = __shfl_xor(ci, mk);
    if (ov > cv || (ov == cv && oi < ci)) { cv = ov; ci = oi; }
  }
  const int e2 = ci; const float v2 = cv;

  if (lane == 0) {
    const float gs = 1.f / (v1 + v2);
    s_g1[wave] = v1 * gs;
    s_g2[wave] = v2 * gs;
    s_pb[wave] = e1 * 8 + e2;
  }
  if (lane < 8) s_imp[wave][eln] = p;   // per-expert prob of this token
  __syncthreads();
  if (tid < 8) {
    float s = 0.f;
#pragma unroll
    for (int wv = 0; wv < 16; ++wv) s += s_imp[wv][tid];
    imp_part[bid * 8 + tid] = s;
  }
  // per-token records (coalesced, block-contiguous)
  if (tid < 16) {
    pbuf[bid * 16 + tid] = s_pb[tid];
    ggbuf[bid * 16 + tid] = make_float2(s_g1[tid], s_g2[tid]);
  }
  // transposed histograms: histT[c*1024 + blk], c in [0,80)
  if (tid < 80) {
    int c = 0;
    if (tid < 16) {
      const int k = tid >> 3, e = tid & 7;
#pragma unroll
      for (int j = 0; j < 16; ++j)
        c += ((k ? (s_pb[j] & 7) : (s_pb[j] >> 3)) == e) ? 1 : 0;
    } else {
      const int b = tid - 16;
#pragma unroll
      for (int j = 0; j < 16; ++j) c += (s_pb[j] == b) ? 1 : 0;
    }
    histT[tid * 1024 + bid] = c;
  }
}

// -------- scan: one block per counter, parallel prefix over 1024 blocks ----
__global__ __launch_bounds__(256) void scan_kernel(
    const int* __restrict__ histT, int* __restrict__ baseT,
    int* __restrict__ cnt, int* __restrict__ cnt_pair) {
  __shared__ int ls[256];
  const int c = blockIdx.x;
  const int t = threadIdx.x;
  const int4 v = ((const int4*)(histT + (c << 10)))[t];
  const int s = v.x + v.y + v.z + v.w;
  ls[t] = s;
  __syncthreads();
#pragma unroll
  for (int off = 1; off < 256; off <<= 1) {
    const int add = (t >= off) ? ls[t - off] : 0;
    __syncthreads();
    ls[t] += add;
    __syncthreads();
  }
  const int incl = ls[t];
  const int excl = incl - s;
  int4 b;
  b.x = excl;
  b.y = excl + v.x;
  b.z = excl + v.x + v.y;
  b.w = excl + v.x + v.y + v.z;
  ((int4*)(baseT + (c << 10)))[t] = b;
  if (t == 255) {
    if (c < 16) cnt[c * 32] = incl;
    else        cnt_pair[(c - 16) * 32] = incl;
  }
}

// -------- scatter (blocks 0..255: pairlist only) + plan (block 256) --------
// Single plan: 64-token pair tiles shared by down AND up (identical tiling).
__global__ __launch_bounds__(256) void scatter_kernel(
    const int* __restrict__ baseT, const int* __restrict__ pbuf,
    const int* __restrict__ cnt_pair,
    int* __restrict__ pairlist,
    int* __restrict__ uplan, int* __restrict__ totals) {
  if (blockIdx.x == 256) {
    __shared__ int uoff[64];
    const int t = threadIdx.x;
    if (t == 0) {
      int a = 0;
      for (int b2 = 0; b2 < 64; ++b2) { uoff[b2] = a; a += (cnt_pair[b2 * 32] + 63) >> 6; }
      totals[1] = a;
    }
    __syncthreads();
    if (t < 64) {
      const int nu = (cnt_pair[t * 32] + 63) >> 6;
      for (int i = 0; i < nu; ++i) uplan[uoff[t] + i] = (t << 16) | i;
    }
    return;
  }
  const int tid = threadIdx.x;
  const int lane = tid & 63;
  const int wave = tid >> 6;
  const int rb = blockIdx.x * 4 + wave;   // router block, 0..1023
  const int i = lane;
  int pb = 0;
  if (lane < 16) pb = pbuf[rb * 16 + lane];
  int rp = 0;
#pragma unroll
  for (int j = 0; j < 15; ++j) {
    const int q = __shfl(pb, j);
    if (j < i) rp += (q == pb) ? 1 : 0;
  }
  if (lane < 16) {
    const int token = rb * 16 + i;
    const int sp = baseT[((16 + pb) << 10) + rb] + rp;
    pairlist[pb * CAP + sp] = token;
  }
}

// ---- down (64-token pair tiles, EXPERT-SPLIT over blockIdx.y): ------------
// y=0 computes H_e1 -> Hbuf[tok], y=1 computes H_e2 -> Hbuf[TOKS+tok].
// BK=128 (8 phases of 2 x 64-k halves; all verified 64-wide index math kept).
// 8 indep loads/thread/phase; grid 576 (2.25 blocks/CU); LDS 33.3KB; Hs
// aliases Bs0 after the K-loop (barrier-protected).
__global__ __launch_bounds__(256) void down_kernel(
    const ushort* __restrict__ xb, const ushort* __restrict__ wdt,
    const int* __restrict__ cnt_pair, const int* __restrict__ pairlist,
    const float2* __restrict__ ggbuf,
    const int* __restrict__ uplan, const int* __restrict__ totals,
    ushort* __restrict__ Hbuf) {
  if (blockIdx.x >= totals[1]) return;
  const int ent = uplan[blockIdx.x];
  const int b = ent >> 16, tile = ent & 0xffff;
  const int y = blockIdx.y;                 // 0 -> e1, 1 -> e2
  const int e = y ? (b & 7) : (b >> 3);
  const int n = cnt_pair[b * 32];
  const int start = tile * 64;

  __shared__ __align__(16) char smem[33280];
  ushort* As0 = (ushort*)(smem);            // 8 KB (64 tok x 64 k, half 0)
  ushort* As1 = (ushort*)(smem + 8192);     // 8 KB (half 1)
  ushort* Bs0 = (ushort*)(smem + 16384);    // 8 KB (64 r x 64 k, half 0)
  ushort* Bs1 = (ushort*)(smem + 24576);    // 8 KB (half 1)
  ushort* Hs  = (ushort*)(smem + 16384);    // aliases Bs0 after K-loop
  int*  toks  = (int*)(smem + 32768);       // 256 B
  float*  gs  = (float*)(smem + 33024);     // 256 B

  const int tid = threadIdx.x;
  const int lane = tid & 63;
  const int w = tid >> 6;

  if (tid < 64) {
    int tk = -1; float g = 0.f;
    if (start + tid < n) {
      tk = pairlist[b * CAP + start + tid];
      const float2 gg = ggbuf[tk];
      g = y ? gg.y : gg.x;
    }
    toks[tid] = tk; gs[tid] = g;
  }
  __syncthreads();

  // staging: thread t covers chunk t (row t>>3) and chunk t+256 (row+32)
  // of each 64x64 half. A: source col swizzled per row (xb natural);
  // B: wdt tiles pre-swizzled in global, LINEAR copy.
  const int row0 = tid >> 3;
  const int g8 = (tid & 7) * 8;
  const int csw = g8 ^ ((row0 & 7) << 3);   // (row0+32)&7 == row0&7
  const int tk0 = toks[row0], tk1 = toks[row0 + 32];
  const ushort* xr0 = xb + (size_t)(tk0 < 0 ? 0 : tk0) * CDIM + csw;
  const ushort* xr1 = xb + (size_t)(tk1 < 0 ? 0 : tk1) * CDIM + csw;
  const ushort* wde = wdt + ((size_t)e << 16);   // 16 tiles x 4096 ushorts

  f32x4 acc[4];
#pragma unroll
  for (int nn = 0; nn < 4; ++nn) acc[nn] = (f32x4){0.f, 0.f, 0.f, 0.f};

  // prefetch registers: rA<half><rowgrp>, rB<half><chunk>
  ushort8 rA00, rA01, rA10, rA11, rB00, rB01, rB10, rB11;
  rA00 = *(const ushort8*)(xr0);
  rA01 = *(const ushort8*)(xr1);
  rA10 = *(const ushort8*)(xr0 + 64);
  rA11 = *(const ushort8*)(xr1 + 64);
  rB00 = *(const ushort8*)(wde + tid * 8);
  rB01 = *(const ushort8*)(wde + tid * 8 + 2048);
  rB10 = *(const ushort8*)(wde + 4096 + tid * 8);
  rB11 = *(const ushort8*)(wde + 4096 + tid * 8 + 2048);

#pragma unroll 1
  for (int s = 0; s < 8; ++s) {
    __syncthreads();                       // prev step's LDS reads done
    *(ushort8*)&As0[tid * 8]        = rA00;
    *(ushort8*)&As0[tid * 8 + 2048] = rA01;
    *(ushort8*)&As1[tid * 8]        = rA10;
    *(ushort8*)&As1[tid * 8 + 2048] = rA11;
    *(ushort8*)&Bs0[tid * 8]        = rB00;
    *(ushort8*)&Bs0[tid * 8 + 2048] = rB01;
    *(ushort8*)&Bs1[tid * 8]        = rB10;
    *(ushort8*)&Bs1[tid * 8 + 2048] = rB11;
    if (s < 7) {                           // prefetch step s+1 under MFMA
      const int k1 = (s + 1) * 128;
      rA00 = *(const ushort8*)(xr0 + k1);
      rA01 = *(const ushort8*)(xr1 + k1);
      rA10 = *(const ushort8*)(xr0 + k1 + 64);
      rA11 = *(const ushort8*)(xr1 + k1 + 64);
      rB00 = *(const ushort8*)(wde + (size_t)(2 * s + 2) * 4096 + tid * 8);
      rB01 = *(const ushort8*)(wde + (size_t)(2 * s + 2) * 4096 + tid * 8 + 2048);
      rB10 = *(const ushort8*)(wde + (size_t)(2 * s + 3) * 4096 + tid * 8);
      rB11 = *(const ushort8*)(wde + (size_t)(2 * s + 3) * 4096 + tid * 8 + 2048);
    }
    __syncthreads();
#pragma unroll
    for (int kk = 0; kk < 128; kk += 32) {
      const ushort* Ah = (kk & 64) ? As1 : As0;
      const ushort* Bh = (kk & 64) ? Bs1 : Bs0;
      const int kb = (kk & 63) + (lane >> 4) * 8;
      bf16x8 a, bb[4];
      {
        const int row = w * 16 + (lane & 15);
        a = *(const bf16x8*)&Ah[row * 64 + (kb ^ ((row & 7) << 3))];
      }
#pragma unroll
      for (int nn = 0; nn < 4; ++nn) {
        const int r = nn * 16 + (lane & 15);
        bb[nn] = *(const bf16x8*)&Bh[r * 64 + (kb ^ ((r & 7) << 3))];
      }
#pragma unroll
      for (int nn = 0; nn < 4; ++nn)
        acc[nn] = __builtin_amdgcn_mfma_f32_16x16x32_bf16(a, bb[nn], acc[nn], 0, 0, 0);
    }
  }
  __syncthreads();                         // all MFMA LDS reads done (alias!)

  // epilogue: GELU*gate -> Hs (wave w owns token slots w*16..w*16+15)
#pragma unroll
  for (int nn = 0; nn < 4; ++nn)
#pragma unroll
    for (int q = 0; q < 4; ++q) {
      const int slot = w * 16 + (lane >> 4) * 4 + q;
      const int r = nn * 16 + (lane & 15);
      const float v = acc[nn][q];
      const float ge = 0.5f * v * (1.f + erff(v * 0.70710678118654752f));
      Hs[slot * 64 + (r ^ ((slot & 7) << 3))] = f2bf(ge * gs[slot]);
    }
  __syncthreads();
  // writeout: thread covers rows row0 and row0+32
  const size_t hb = (size_t)y * TOKS;
  const int lof0 = row0 * 64 + (g8 ^ ((row0 & 7) << 3));
  const int lof1 = (row0 + 32) * 64 + (g8 ^ ((row0 & 7) << 3));
  if (tk0 >= 0)
    *(ushort8*)(Hbuf + (hb + tk0) * 64 + g8) = *(const ushort8*)&Hs[lof0];
  if (tk1 >= 0)
    *(ushort8*)(Hbuf + (hb + tk1) * 64 + g8) = *(const ushort8*)&Hs[lof1];
}

// ---- up: out[t] = H0[t]@Wu_ea + H1[t]@Wu_eb, 64-tok x 2 col-slices --------
// (verified r9-r13) A0/A1 staged ONCE per block; slice-1 weights
// reg-prefetched under slice-0 MFMAs. Block x==UT_MAX runs aux.
__global__ __launch_bounds__(256) void up_kernel(
    const ushort* __restrict__ Hbuf, const ushort* __restrict__ wut,
    const int* __restrict__ cnt_pair, const int* __restrict__ pairlist,
    const int* __restrict__ uplan, const int* __restrict__ totals,
    const int* __restrict__ cnt, const float* __restrict__ imp_part,
    float* __restrict__ out) {
  __shared__ __align__(16) char smem[49664];
  if (blockIdx.x == UT_MAX) {          // aux block (y==0 only)
    if (blockIdx.y != 0) return;
    float* red = (float*)smem;
    float* tot = (float*)(smem + 1024);
    const int t = threadIdx.x;
    const int e = t & 7, b0 = t >> 3;
    float s = 0.f;
    for (int j = 0; j < NBLK_R / 32; ++j)
      s += imp_part[(b0 + 32 * j) * 8 + e];
    red[t] = s;
    __syncthreads();
    if (t < 8) {
      float tt = 0.f;
      for (int ww = 0; ww < 32; ++ww) tt += red[ww * 8 + t];
      tot[t] = tt;
    }
    __syncthreads();
    if (t == 0) {
      float a = 0.f;
#pragma unroll
      for (int ee = 0; ee < NEXP; ++ee)
        a += (tot[ee] / (float)TOKS) *
             ((float)(cnt[ee * 32] + cnt[(NEXP + ee) * 32]) / (float)(2 * TOKS));
      out[(size_t)TOKS * CDIM] = 0.001f * 8.f * a;
    }
    return;
  }
  if (blockIdx.x >= totals[1]) return;
  const int ent = uplan[blockIdx.x];
  const int b = ent >> 16, tile = ent & 0xffff;
  const int ea = b >> 3, eb = b & 7;
  const int n = cnt_pair[b * 32];
  const int start = tile * 64;
  const int ybase = blockIdx.y * 2;    // 2 slices per block

  ushort* A0  = (ushort*)(smem);            // 8 KB (64x64)
  ushort* A1  = (ushort*)(smem + 8192);     // 8 KB
  ushort* BuA = (ushort*)(smem + 16384);    // 16 KB (128x64)
  ushort* BuB = (ushort*)(smem + 32768);    // 16 KB
  int*  toks  = (int*)(smem + 49152);       // 256 B

  const int tid = threadIdx.x;
  const int lane = tid & 63;
  const int w = tid >> 6;
  const int wr = w >> 1, wc = w & 1;

  if (tid < 64) {
    int tk = -1;
    if (start + tid < n) tk = pairlist[b * CAP + start + tid];
    toks[tid] = tk;
  }
  __syncthreads();

  // issue slice-0 weight loads (pre-swizzled wut; linear copy)
  const ushort* wuA = wut + ((size_t)(ea * 8 + ybase)) * 8192;
  const ushort* wuB = wut + ((size_t)(eb * 8 + ybase)) * 8192;
  ushort8 rUA[4], rUB[4];
#pragma unroll
  for (int j = 0; j < 4; ++j) {
    rUA[j] = *(const ushort8*)(wuA + (tid + j * 256) * 8);
    rUB[j] = *(const ushort8*)(wuB + (tid + j * 256) * 8);
  }
  // A-gather (source col swizzled; LDS linear) — ONCE per block
  const int row0 = tid >> 3;
  const int g8 = (tid & 7) * 8;
  const int csw = g8 ^ ((row0 & 7) << 3);
  const int tk0 = toks[row0], tk1 = toks[row0 + 32];
  const size_t t0 = (size_t)(tk0 < 0 ? 0 : tk0);
  const size_t t1 = (size_t)(tk1 < 0 ? 0 : tk1);
  *(ushort8*)&A0[tid * 8]        = *(const ushort8*)(Hbuf + t0 * 64 + csw);
  *(ushort8*)&A0[tid * 8 + 2048] = *(const ushort8*)(Hbuf + t1 * 64 + csw);
  *(ushort8*)&A1[tid * 8]        = *(const ushort8*)(Hbuf + (TOKS + t0) * 64 + csw);
  *(ushort8*)&A1[tid * 8 + 2048] = *(const ushort8*)(Hbuf + (TOKS + t1) * 64 + csw);
  // write slice-0 weights
#pragma unroll
  for (int j = 0; j < 4; ++j) {
    *(ushort8*)&BuA[(tid + j * 256) * 8] = rUA[j];
    *(ushort8*)&BuB[(tid + j * 256) * 8] = rUB[j];
  }
  __syncthreads();

#pragma unroll 1
  for (int j2 = 0; j2 < 2; ++j2) {
    const int n0 = ybase + j2;
    if (j2 == 0) {                      // prefetch slice-1 weights under MFMA
#pragma unroll
      for (int j = 0; j < 4; ++j) {
        rUA[j] = *(const ushort8*)(wuA + 8192 + (tid + j * 256) * 8);
        rUB[j] = *(const ushort8*)(wuB + 8192 + (tid + j * 256) * 8);
      }
    }
    f32x4 uac[2][4];
#pragma unroll
    for (int m = 0; m < 2; ++m)
#pragma unroll
      for (int nn = 0; nn < 4; ++nn) uac[m][nn] = (f32x4){0.f, 0.f, 0.f, 0.f};
    // pass A: H0 @ Wu_ea
#pragma unroll
    for (int kk = 0; kk < 64; kk += 32) {
      const int kb = kk + (lane >> 4) * 8;
      bf16x8 a[2], bbv[4];
#pragma unroll
      for (int m = 0; m < 2; ++m) {
        const int row = wr * 32 + m * 16 + (lane & 15);
        a[m] = *(const bf16x8*)&A0[row * 64 + (kb ^ ((row & 7) << 3))];
      }
#pragma unroll
      for (int nn = 0; nn < 4; ++nn) {
        const int c = wc * 64 + nn * 16 + (lane & 15);
        bbv[nn] = *(const bf16x8*)&BuA[c * 64 + (kb ^ ((c & 7) << 3))];
      }
#pragma unroll
      for (int m = 0; m < 2; ++m)
#pragma unroll
        for (int nn = 0; nn < 4; ++nn)
          uac[m][nn] = __builtin_amdgcn_mfma_f32_16x16x32_bf16(a[m], bbv[nn], uac[m][nn], 0, 0, 0);
    }
    // pass B: H1 @ Wu_eb (accumulate)
#pragma unroll
    for (int kk = 0; kk < 64; kk += 32) {
      const int kb = kk + (lane >> 4) * 8;
      bf16x8 a[2], bbv[4];
#pragma unroll
      for (int m = 0; m < 2; ++m) {
        const int row = wr * 32 + m * 16 + (lane & 15);
        a[m] = *(const bf16x8*)&A1[row * 64 + (kb ^ ((row & 7) << 3))];
      }
#pragma unroll
      for (int nn = 0; nn < 4; ++nn) {
        const int c = wc * 64 + nn * 16 + (lane & 15);
        bbv[nn] = *(const bf16x8*)&BuB[c * 64 + (kb ^ ((c & 7) << 3))];
      }
#pragma unroll
      for (int m = 0; m < 2; ++m)
#pragma unroll
        for (int nn = 0; nn < 4; ++nn)
          uac[m][nn] = __builtin_amdgcn_mfma_f32_16x16x32_bf16(a[m], bbv[nn], uac[m][nn], 0, 0, 0);
    }
    if (j2 == 0) {
      __syncthreads();                  // all waves done reading Bu
#pragma unroll
      for (int j = 0; j < 4; ++j) {
        *(ushort8*)&BuA[(tid + j * 256) * 8] = rUA[j];
        *(ushort8*)&BuB[(tid + j * 256) * 8] = rUB[j];
      }
    }
    // store this 128-col slice
#pragma unroll
    for (int m = 0; m < 2; ++m)
#pragma unroll
      for (int q = 0; q < 4; ++q) {
        const int slot = wr * 32 + m * 16 + (lane >> 4) * 4 + q;
        const int tk = toks[slot];
        if (tk >= 0) {
          float* orow = out + (size_t)tk * CDIM + n0 * 128 + wc * 64 + (lane & 15);
#pragma unroll
          for (int nn = 0; nn < 4; ++nn) orow[nn * 16] = uac[m][nn][q];
        }
      }
    if (j2 == 0) __syncthreads();       // Bu writes visible for slice 1
  }
}

extern "C" void kernel_launch(void* const* d_in, const int* in_sizes, int n_in,
                              void* d_out, int out_size, void* d_ws, size_t ws_size,
                              hipStream_t stream) {
  const float* x   = (const float*)d_in[0];
  const float* rw  = (const float*)d_in[1];
  const float* rb  = (const float*)d_in[2];
  const float* Wd  = (const float*)d_in[3];
  const float* Wu  = (const float*)d_in[4];
  const int* key_id = (const int*)d_in[5];
  float* out = (float*)d_out;

  char* ws = (char*)d_ws;
  int*    cnt      = (int*)ws;                    // 2 KB  (16 x 128B)
  int*    cnt_pair = (int*)(ws + 2048);           // 8 KB  (64 x 128B)
  int*    totals   = (int*)(ws + 10240);          // 8 B
  float*  imp_part = (float*)(ws + 16384);        // 32 KB
  int*    uplan    = (int*)(ws + 57344);          // ~1.3 KB
  int*    pbuf     = (int*)(ws + 65536);          // 64 KB
  float2* ggbuf    = (float2*)(ws + 131072);      // 128 KB (read by down)
  ushort* wdt      = (ushort*)(ws + 2162688);     // 1 MB
  ushort* wut      = (ushort*)(ws + 3211264);     // 1 MB
  ushort* xb       = (ushort*)(ws + 4259840);     // 32 MB -> 37814272
  int*    pairlist = (int*)(ws + 37847040);       // 4 MB  -> 42041344
  ushort* Hbuf     = (ushort*)(ws + 42041344);    // 4 MB  -> 46235648

  // histT/baseT ALIAS the Hbuf region: fully consumed by scan/scatter before
  // down_kernel writes Hbuf.
  int*    histT = (int*)(ws + 42041344);                // 320 KB
  int*    baseT = (int*)(ws + 42041344 + 327680);       // 320 KB

  setup_kernel<<<NBLK_R + 256, 1024, 0, stream>>>(
      x, rw, rb, key_id, Wd, Wu, imp_part, pbuf, ggbuf, histT, xb, wdt, wut);
  scan_kernel<<<80, 256, 0, stream>>>(histT, baseT, cnt, cnt_pair);
  scatter_kernel<<<257, 256, 0, stream>>>(baseT, pbuf, cnt_pair,
                                          pairlist, uplan, totals);
  down_kernel<<<dim3(UT_MAX, 2), 256, 0, stream>>>(
      xb, wdt, cnt_pair, pairlist, ggbuf, uplan, totals, Hbuf);
  up_kernel<<<dim3(UT_MAX + 1, 4), 256, 0, stream>>>(
      Hbuf, wut, cnt_pair, pairlist, uplan, totals, cnt, imp_part, out);
}